// Round 1
// baseline (422.472 us; speedup 1.0000x reference)
//
#include <hip/hip_runtime.h>
#include <cstdint>
#include <cstddef>

#define NROWS   32768
#define DIM     1024
#define NH      4
#define HD      256
#define NK      64
#define RPB     8            // rows per block
#define STRIDE  1028         // 1024 + 4 floats pad -> row bank-offset rotates by 4
#define NBLK    (NROWS / RPB)
#define THREADS 128

__device__ __forceinline__ float wave_allreduce_sum(float v) {
  #pragma unroll
  for (int m = 1; m < 64; m <<= 1) v += __shfl_xor(v, m, 64);
  return v;
}

#define DOT4(A, X, ACC)                 \
  ACC = fmaf((A).x, (X).x, ACC);        \
  ACC = fmaf((A).y, (X).y, ACC);        \
  ACC = fmaf((A).z, (X).z, ACC);        \
  ACC = fmaf((A).w, (X).w, ACC);

__global__ __launch_bounds__(THREADS) void vq_main(
    const float* __restrict__ in, const float* __restrict__ lnw,
    const float* __restrict__ lnb, const float* __restrict__ emb,
    float* __restrict__ out, float* __restrict__ ws)
{
  __shared__ __align__(16) float xs[RPB * STRIDE];
  __shared__ float inv_s[RPB];
  __shared__ float base_s[RPB];                 // 4 + ssx*inv^2
  __shared__ __align__(16) int bidx_s[RPB][NH];
  __shared__ float bval_s[RPB][NH];

  float* loss_acc = ws;
  int*   present  = (int*)(ws + 16);

  const int tid  = threadIdx.x;
  const int wave = tid >> 6;      // 0..1
  const int lane = tid & 63;
  const int row0 = blockIdx.x * RPB;

  // ---------------- Phase A: LN + soft-clip, 4 rows per wave ----------------
  float4 wv[4], bvv4[4];
  #pragma unroll
  for (int c = 0; c < 4; ++c) {
    wv[c]   = *(const float4*)(lnw + c * 256 + lane * 4);
    bvv4[c] = *(const float4*)(lnb + c * 256 + lane * 4);
  }

  #pragma unroll
  for (int rr = 0; rr < 4; ++rr) {
    const int r = wave * 4 + rr;
    const float* rp = in + (size_t)(row0 + r) * DIM;
    float4 v[4];
    #pragma unroll
    for (int c = 0; c < 4; ++c) v[c] = *(const float4*)(rp + c * 256 + lane * 4);

    float s1 = 0.f, s2 = 0.f;
    #pragma unroll
    for (int c = 0; c < 4; ++c) {
      s1 += (v[c].x + v[c].y) + (v[c].z + v[c].w);
      s2 = fmaf(v[c].x, v[c].x, s2); s2 = fmaf(v[c].y, v[c].y, s2);
      s2 = fmaf(v[c].z, v[c].z, s2); s2 = fmaf(v[c].w, v[c].w, s2);
    }
    s1 = wave_allreduce_sum(s1);
    s2 = wave_allreduce_sum(s2);
    const float mu   = s1 * (1.0f / 1024.0f);
    const float var  = fmaf(-mu, mu, s2 * (1.0f / 1024.0f));
    const float rstd = rsqrtf(var + 1e-5f);

    float ss = 0.f;
    #pragma unroll
    for (int c = 0; c < 4; ++c) {
      float*       pv = reinterpret_cast<float*>(&v[c]);
      const float* pw = reinterpret_cast<const float*>(&wv[c]);
      const float* pb = reinterpret_cast<const float*>(&bvv4[c]);
      #pragma unroll
      for (int i = 0; i < 4; ++i) {
        float xh = (pv[i] - mu) * rstd;
        xh = fmaf(xh, pw[i], pb[i]);
        // 5*tanh(xh/5) = 5*(1 - 2/(e^{0.4*xh}+1))
        const float e = __expf(0.4f * xh);
        const float t = 1.f - 2.f * __builtin_amdgcn_rcpf(e + 1.f);
        const float xx = 5.f * t;
        ss = fmaf(xx, xx, ss);
        pv[i] = xx;
      }
    }
    ss = wave_allreduce_sum(ss);

    #pragma unroll
    for (int c = 0; c < 4; ++c)
      *(float4*)(&xs[r * STRIDE + c * 256 + lane * 4]) = v[c];

    if (lane == 0) {
      const float nrm = sqrtf(ss);
      const float iv  = 1.f / fmaxf(nrm, 1e-5f);
      inv_s[r]  = iv;
      base_s[r] = fmaf(ss * iv, iv, 4.f);   // ||q||^2(=4) + ||xn||^2
    }
  }
  __syncthreads();

  // ---------------- Phase B: distances. thread = (h, kgroup, rowgroup) ------
  const int h  = tid >> 5;          // 0..3
  const int kg = (tid >> 1) & 15;   // 0..15
  const int rg = tid & 1;           // 0..1

  const float* e0 = emb + (size_t)(h * NK + kg * 4 + 0) * HD;
  const float* e1 = e0 + HD;
  const float* e2 = e0 + 2 * HD;
  const float* e3 = e0 + 3 * HD;
  const float* x0 = xs + (rg * 4 + 0) * STRIDE + h * HD;
  const float* x1 = x0 + STRIDE;
  const float* x2 = x0 + 2 * STRIDE;
  const float* x3 = x0 + 3 * STRIDE;

  float acc[4][4] = {};
  #pragma unroll 2
  for (int j = 0; j < HD; j += 4) {
    const float4 ea = *(const float4*)(e0 + j);
    const float4 eb = *(const float4*)(e1 + j);
    const float4 ec = *(const float4*)(e2 + j);
    const float4 ed = *(const float4*)(e3 + j);
    const float4 xa = *(const float4*)(x0 + j);
    const float4 xb = *(const float4*)(x1 + j);
    const float4 xc = *(const float4*)(x2 + j);
    const float4 xd = *(const float4*)(x3 + j);
    DOT4(ea, xa, acc[0][0]) DOT4(ea, xb, acc[0][1]) DOT4(ea, xc, acc[0][2]) DOT4(ea, xd, acc[0][3])
    DOT4(eb, xa, acc[1][0]) DOT4(eb, xb, acc[1][1]) DOT4(eb, xc, acc[1][2]) DOT4(eb, xd, acc[1][3])
    DOT4(ec, xa, acc[2][0]) DOT4(ec, xb, acc[2][1]) DOT4(ec, xc, acc[2][2]) DOT4(ec, xd, acc[2][3])
    DOT4(ed, xa, acc[3][0]) DOT4(ed, xb, acc[3][1]) DOT4(ed, xc, acc[3][2]) DOT4(ed, xd, acc[3][3])
  }

  // argmax over k: local 4, then butterfly across 16 kgroups (lane-xor 2,4,8,16)
  #pragma unroll
  for (int rr = 0; rr < 4; ++rr) {
    float bv = acc[0][rr];
    int   bi = kg * 4;
    #pragma unroll
    for (int kk = 1; kk < 4; ++kk) {
      if (acc[kk][rr] > bv) { bv = acc[kk][rr]; bi = kg * 4 + kk; }
    }
    #pragma unroll
    for (int m = 2; m <= 16; m <<= 1) {
      const float ov = __shfl_xor(bv, m, 64);
      const int   oi = __shfl_xor(bi, m, 64);
      if (ov > bv || (ov == bv && oi < bi)) { bv = ov; bi = oi; }
    }
    if (kg == 0) {
      const int r = rg * 4 + rr;
      bidx_s[r][h] = bi;
      bval_s[r][h] = bv;
      present[bi] = 1;          // benign race: everyone writes 1
    }
  }
  __syncthreads();

  // ---------------- Phase C: gather-write q, loss ---------------------------
  float lsum = 0.f;
  #pragma unroll
  for (int rr = 0; rr < 4; ++rr) {
    const int r = wave * 4 + rr;
    const int4 bi = *(const int4*)(&bidx_s[r][0]);
    const float4 q0 = *(const float4*)(emb + (size_t)(0 * NK + bi.x) * HD + lane * 4);
    const float4 q1 = *(const float4*)(emb + (size_t)(1 * NK + bi.y) * HD + lane * 4);
    const float4 q2 = *(const float4*)(emb + (size_t)(2 * NK + bi.z) * HD + lane * 4);
    const float4 q3 = *(const float4*)(emb + (size_t)(3 * NK + bi.w) * HD + lane * 4);
    float* op = out + (size_t)(row0 + r) * DIM + lane * 4;
    *(float4*)(op + 0)   = q0;
    *(float4*)(op + 256) = q1;
    *(float4*)(op + 512) = q2;
    *(float4*)(op + 768) = q3;
    if (lane == 0) {
      const float iv = inv_s[r];
      const float ds = (bval_s[r][0] + bval_s[r][1]) + (bval_s[r][2] + bval_s[r][3]);
      lsum += fmaf(-2.f * iv, ds, base_s[r]);   // ||q-xn||^2 for this row
    }
  }
  if (lane == 0) atomicAdd(loss_acc, lsum);
}

__global__ void vq_fin(const float* __restrict__ ws, float* __restrict__ out) {
  const int t = threadIdx.x;
  const int* present = (const int*)(ws + 16);
  const unsigned long long m = __ballot(present[t] != 0);
  if (t == 0) {
    out[33554432] = 0.25f * ws[0] / 33554432.0f;
    out[33554433] = (float)__popcll(m);
  }
}

extern "C" void kernel_launch(void* const* d_in, const int* in_sizes, int n_in,
                              void* d_out, int out_size, void* d_ws, size_t ws_size,
                              hipStream_t stream) {
  const float* in  = (const float*)d_in[0];
  const float* lnw = (const float*)d_in[1];
  const float* lnb = (const float*)d_in[2];
  const float* emb = (const float*)d_in[3];
  float* out = (float*)d_out;
  float* ws  = (float*)d_ws;

  // zero loss accumulator (ws[0]) + present flags (64 ints at ws+16)
  hipMemsetAsync(d_ws, 0, (16 + 64) * sizeof(float), stream);
  vq_main<<<NBLK, THREADS, 0, stream>>>(in, lnw, lnb, emb, out, ws);
  vq_fin<<<1, 64, 0, stream>>>(ws, out);
}

// Round 2
// 355.696 us; speedup vs baseline: 1.1877x; 1.1877x over previous
//
#include <hip/hip_runtime.h>
#include <cstdint>
#include <cstddef>

#define NROWS   32768
#define DIM     1024
#define NH      4
#define HD      256
#define NK      64
#define RPB     8            // rows per block
#define STRIDE  1028         // 1024 + 4 floats pad
#define NBLK    (NROWS / RPB)   // 4096
#define THREADS 256

__device__ __forceinline__ float wave_allreduce_sum(float v) {
  #pragma unroll
  for (int m = 1; m < 64; m <<= 1) v += __shfl_xor(v, m, 64);
  return v;
}

#define DOT4(A, X, ACC)                 \
  ACC = fmaf((A).x, (X).x, ACC);        \
  ACC = fmaf((A).y, (X).y, ACC);        \
  ACC = fmaf((A).z, (X).z, ACC);        \
  ACC = fmaf((A).w, (X).w, ACC);

__global__ __launch_bounds__(THREADS, 4) void vq_main(
    const float* __restrict__ in, const float* __restrict__ lnw,
    const float* __restrict__ lnb, const float* __restrict__ emb,
    float* __restrict__ out, float* __restrict__ ws)
{
  __shared__ __align__(16) float xs[RPB * STRIDE];   // 32.9 KB
  __shared__ float inv_s[RPB];
  __shared__ float base_s[RPB];                      // 4 + ssx*inv^2
  __shared__ __align__(16) int bidx_s[RPB][NH];
  __shared__ float bval_s[RPB][NH];

  float* ws_loss = ws;                                             // [NBLK]
  unsigned long long* ws_mask = (unsigned long long*)(ws + NBLK);  // [NBLK]

  const int tid  = threadIdx.x;
  const int wave = tid >> 6;      // 0..3
  const int lane = tid & 63;
  const int row0 = blockIdx.x * RPB;

  // ---------------- Phase A: LN + soft-clip; wave handles 2 rows ------------
  float4 wv[4], bv4[4];
  #pragma unroll
  for (int c = 0; c < 4; ++c) {
    wv[c]  = *(const float4*)(lnw + c * 256 + lane * 4);
    bv4[c] = *(const float4*)(lnb + c * 256 + lane * 4);
  }

  #pragma unroll
  for (int rr = 0; rr < 2; ++rr) {
    const int r = wave * 2 + rr;
    const float* rp = in + (size_t)(row0 + r) * DIM;
    float4 v[4];
    #pragma unroll
    for (int c = 0; c < 4; ++c) v[c] = *(const float4*)(rp + c * 256 + lane * 4);

    float s1 = 0.f, s2 = 0.f;
    #pragma unroll
    for (int c = 0; c < 4; ++c) {
      s1 += (v[c].x + v[c].y) + (v[c].z + v[c].w);
      s2 = fmaf(v[c].x, v[c].x, s2); s2 = fmaf(v[c].y, v[c].y, s2);
      s2 = fmaf(v[c].z, v[c].z, s2); s2 = fmaf(v[c].w, v[c].w, s2);
    }
    s1 = wave_allreduce_sum(s1);
    s2 = wave_allreduce_sum(s2);
    const float mu   = s1 * (1.0f / 1024.0f);
    const float var  = fmaf(-mu, mu, s2 * (1.0f / 1024.0f));
    const float rstd = rsqrtf(var + 1e-5f);

    float ss = 0.f;
    #pragma unroll
    for (int c = 0; c < 4; ++c) {
      float*       pv = reinterpret_cast<float*>(&v[c]);
      const float* pw = reinterpret_cast<const float*>(&wv[c]);
      const float* pb = reinterpret_cast<const float*>(&bv4[c]);
      #pragma unroll
      for (int i = 0; i < 4; ++i) {
        float xh = (pv[i] - mu) * rstd;
        xh = fmaf(xh, pw[i], pb[i]);
        // 5*tanh(xh/5) = 5*(1 - 2/(e^{0.4*xh}+1))
        const float e = __expf(0.4f * xh);
        const float t = 1.f - 2.f * __builtin_amdgcn_rcpf(e + 1.f);
        const float xx = 5.f * t;
        ss = fmaf(xx, xx, ss);
        pv[i] = xx;
      }
    }
    ss = wave_allreduce_sum(ss);

    #pragma unroll
    for (int c = 0; c < 4; ++c)
      *(float4*)(&xs[r * STRIDE + c * 256 + lane * 4]) = v[c];

    if (lane == 0) {
      const float nrm = sqrtf(ss);
      const float iv  = 1.f / fmaxf(nrm, 1e-5f);
      inv_s[r]  = iv;
      base_s[r] = fmaf(ss * iv, iv, 4.f);   // ||q||^2(=4) + ||xn||^2
    }
  }
  __syncthreads();

  // ---------------- Phase B: distances. wave = head; lane = (kg, rg) --------
  const int h  = wave;            // head
  const int kg = lane >> 2;       // 0..15 -> 4 codes each
  const int rg = lane & 3;        // 0..3  -> 2 rows each

  const float* eb = emb + ((size_t)h * NK + kg * 4) * HD;
  const float* xb = xs + (rg * 2) * STRIDE + h * HD;

  float acc[4][2] = {};
  #pragma unroll 2
  for (int j = 0; j < HD; j += 4) {
    const float4 e0 = *(const float4*)(eb + 0 * HD + j);
    const float4 e1 = *(const float4*)(eb + 1 * HD + j);
    const float4 e2 = *(const float4*)(eb + 2 * HD + j);
    const float4 e3 = *(const float4*)(eb + 3 * HD + j);
    const float4 x0 = *(const float4*)(xb + j);
    const float4 x1 = *(const float4*)(xb + STRIDE + j);
    DOT4(e0, x0, acc[0][0]) DOT4(e0, x1, acc[0][1])
    DOT4(e1, x0, acc[1][0]) DOT4(e1, x1, acc[1][1])
    DOT4(e2, x0, acc[2][0]) DOT4(e2, x1, acc[2][1])
    DOT4(e3, x0, acc[3][0]) DOT4(e3, x1, acc[3][1])
  }

  // argmax over k: local 4, then butterfly across kg (xor 4,8,16,32)
  #pragma unroll
  for (int rr = 0; rr < 2; ++rr) {
    float bv = acc[0][rr];
    int   bi = kg * 4;
    #pragma unroll
    for (int kk = 1; kk < 4; ++kk) {
      if (acc[kk][rr] > bv) { bv = acc[kk][rr]; bi = kg * 4 + kk; }
    }
    #pragma unroll
    for (int m = 4; m <= 32; m <<= 1) {
      const float ov = __shfl_xor(bv, m, 64);
      const int   oi = __shfl_xor(bi, m, 64);
      if (ov > bv || (ov == bv && oi < bi)) { bv = ov; bi = oi; }
    }
    if (kg == 0) {
      const int r = rg * 2 + rr;
      bidx_s[r][h] = bi;
      bval_s[r][h] = bv;
    }
  }
  __syncthreads();

  // ---------------- Phase C: gather-write q; wave 0 does loss+present -------
  #pragma unroll
  for (int rr = 0; rr < 2; ++rr) {
    const int r = wave * 2 + rr;
    const int4 bi = *(const int4*)(&bidx_s[r][0]);
    const float4 q0 = *(const float4*)(emb + (size_t)(0 * NK + bi.x) * HD + lane * 4);
    const float4 q1 = *(const float4*)(emb + (size_t)(1 * NK + bi.y) * HD + lane * 4);
    const float4 q2 = *(const float4*)(emb + (size_t)(2 * NK + bi.z) * HD + lane * 4);
    const float4 q3 = *(const float4*)(emb + (size_t)(3 * NK + bi.w) * HD + lane * 4);
    float* op = out + (size_t)(row0 + r) * DIM + lane * 4;
    *(float4*)(op + 0)   = q0;
    *(float4*)(op + 256) = q1;
    *(float4*)(op + 512) = q2;
    *(float4*)(op + 768) = q3;
  }

  if (wave == 0) {
    // per-row loss on lanes 0..7, reduce within lanes 0..7 (xor 1,2,4)
    float lsum = 0.f;
    if (lane < 8) {
      const float ds = (bval_s[lane][0] + bval_s[lane][1]) +
                       (bval_s[lane][2] + bval_s[lane][3]);
      lsum = fmaf(-2.f * inv_s[lane], ds, base_s[lane]);
    }
    #pragma unroll
    for (int m = 1; m <= 4; m <<= 1) lsum += __shfl_xor(lsum, m, 64);

    // present: lane j checks whether any of the 32 chosen indices == j
    const int* bf = &bidx_s[0][0];
    bool found = false;
    #pragma unroll
    for (int i = 0; i < 32; ++i) found |= (bf[i] == lane);
    const unsigned long long m = __ballot(found);

    if (lane == 0) {
      ws_loss[blockIdx.x] = lsum;
      ws_mask[blockIdx.x] = m;
    }
  }
}

__global__ __launch_bounds__(256) void vq_fin(const float* __restrict__ ws,
                                              float* __restrict__ out) {
  __shared__ float ls[4];
  __shared__ unsigned long long ms[4];
  const float* ws_loss = ws;
  const unsigned long long* ws_mask = (const unsigned long long*)(ws + NBLK);

  const int tid = threadIdx.x, wave = tid >> 6, lane = tid & 63;
  float l = 0.f;
  unsigned long long m = 0ull;
  for (int i = tid; i < NBLK; i += 256) { l += ws_loss[i]; m |= ws_mask[i]; }
  #pragma unroll
  for (int s = 1; s < 64; s <<= 1) {
    l += __shfl_xor(l, s, 64);
    m |= __shfl_xor(m, s, 64);
  }
  if (lane == 0) { ls[wave] = l; ms[wave] = m; }
  __syncthreads();
  if (tid == 0) {
    const float total = (ls[0] + ls[1]) + (ls[2] + ls[3]);
    const unsigned long long mm = ms[0] | ms[1] | ms[2] | ms[3];
    out[33554432] = 0.25f * total / 33554432.0f;
    out[33554433] = (float)__popcll(mm);
  }
}

extern "C" void kernel_launch(void* const* d_in, const int* in_sizes, int n_in,
                              void* d_out, int out_size, void* d_ws, size_t ws_size,
                              hipStream_t stream) {
  const float* in  = (const float*)d_in[0];
  const float* lnw = (const float*)d_in[1];
  const float* lnb = (const float*)d_in[2];
  const float* emb = (const float*)d_in[3];
  float* out = (float*)d_out;
  float* ws  = (float*)d_ws;

  vq_main<<<NBLK, THREADS, 0, stream>>>(in, lnw, lnb, emb, out, ws);
  vq_fin<<<1, 256, 0, stream>>>(ws, out);
}

// Round 3
// 258.737 us; speedup vs baseline: 1.6328x; 1.3747x over previous
//
#include <hip/hip_runtime.h>
#include <cstdint>
#include <cstddef>

#define NROWS   32768
#define DIM     1024
#define NH      4
#define HD      256
#define NK      64
#define RPB     16           // rows per block = one MFMA M-tile
#define NBLK    (NROWS / RPB)   // 2048
#define THREADS 256

typedef __attribute__((ext_vector_type(8))) short short8;   // 8 bf16 (4 VGPRs)
typedef __attribute__((ext_vector_type(4))) float float4a;  // MFMA acc

__device__ __forceinline__ unsigned short f2bf(float f) {
  unsigned int u = __float_as_uint(f);
  u += 0x7fffu + ((u >> 16) & 1u);   // RNE (no NaN inputs here)
  return (unsigned short)(u >> 16);
}

// ---------------------------------------------------------------------------
// Pre-kernel: emb fp32 [4][64][256] -> bf16 B-fragment-linear layout in ws.
// granule g = ((h*4 + t)*8 + s)*64 + lane holds 8 bf16:
//   emb[h][t*16 + (lane&15)][s*32 + (lane>>4)*8 + 0..7]
// ---------------------------------------------------------------------------
__global__ __launch_bounds__(256) void vq_pre(const float* __restrict__ emb,
                                              unsigned short* __restrict__ ws_emb) {
  const int gid  = blockIdx.x * 256 + threadIdx.x;   // 0..8191
  const int lane = gid & 63;
  const int w    = gid >> 6;                          // (h*4 + t)*8 + s
  const int s = w & 7, ht = w >> 3, t = ht & 3, h = ht >> 2;
  const int code = t * 16 + (lane & 15);
  const int d0   = s * 32 + (lane >> 4) * 8;
  const float* p = emb + ((size_t)(h * NK + code)) * HD + d0;
  unsigned int w0 = f2bf(p[0]) | ((unsigned int)f2bf(p[1]) << 16);
  unsigned int w1 = f2bf(p[2]) | ((unsigned int)f2bf(p[3]) << 16);
  unsigned int w2 = f2bf(p[4]) | ((unsigned int)f2bf(p[5]) << 16);
  unsigned int w3 = f2bf(p[6]) | ((unsigned int)f2bf(p[7]) << 16);
  uint4 pk = make_uint4(w0, w1, w2, w3);
  *(uint4*)(ws_emb + (size_t)(w * 64 + lane) * 8) = pk;
}

// ---------------------------------------------------------------------------
// Main kernel: 16 rows/block. Phase A: LN+softclip -> bf16 A-frags in LDS.
// Phase B: wave=head, 32 MFMAs -> dist[16 rows][64 codes], argmax butterfly.
// Phase C: gather-write q, per-block loss + present mask.
// ---------------------------------------------------------------------------
__global__ __launch_bounds__(THREADS, 4) void vq_main(
    const float* __restrict__ in, const float* __restrict__ lnw,
    const float* __restrict__ lnb, const float* __restrict__ emb,
    const unsigned short* __restrict__ ws_emb,
    float* __restrict__ out, float* __restrict__ ws)
{
  // x tile, bf16, fragment-swizzled: granule ((h*8+s)*4+q)*16 + (m^(q<<2)^s)
  __shared__ __align__(16) unsigned short xs[NH * 8 * 4 * 16 * 8]; // 32 KB
  __shared__ float inv_s[RPB];
  __shared__ float base_s[RPB];                  // 4 + ssx*inv^2
  __shared__ __align__(16) int bidx_s[RPB][NH];
  __shared__ float bval_s[RPB][NH];
  __shared__ int flags_s[NH][NK];                // per-head present flags

  float* ws_loss = ws;                                             // [NBLK]
  unsigned long long* ws_mask = (unsigned long long*)(ws + NBLK);  // [NBLK]

  const int tid  = threadIdx.x;
  const int wave = tid >> 6;      // 0..3
  const int lane = tid & 63;
  const int row0 = blockIdx.x * RPB;

  flags_s[tid >> 6][tid & 63] = 0;   // 256 ints, exactly one per thread

  // ---------------- Phase A: LN + soft-clip; wave handles 4 rows ------------
  float4 wv[4], bv4[4];
  #pragma unroll
  for (int c = 0; c < 4; ++c) {
    wv[c]  = *(const float4*)(lnw + c * 256 + lane * 4);
    bv4[c] = *(const float4*)(lnb + c * 256 + lane * 4);
  }

  const int sA = lane >> 3;          // k-step of this lane's dims
  const int qA = (lane >> 1) & 3;    // k-octet quad
  const int hfA = lane & 1;          // low/high half of octet

  #pragma unroll
  for (int rr = 0; rr < 4; ++rr) {
    const int m = wave * 4 + rr;     // row within block
    const float* rp = in + (size_t)(row0 + m) * DIM;
    float4 v[4];
    #pragma unroll
    for (int c = 0; c < 4; ++c) v[c] = *(const float4*)(rp + c * 256 + lane * 4);

    float s1 = 0.f, s2 = 0.f;
    #pragma unroll
    for (int c = 0; c < 4; ++c) {
      s1 += (v[c].x + v[c].y) + (v[c].z + v[c].w);
      s2 = fmaf(v[c].x, v[c].x, s2); s2 = fmaf(v[c].y, v[c].y, s2);
      s2 = fmaf(v[c].z, v[c].z, s2); s2 = fmaf(v[c].w, v[c].w, s2);
    }
    #pragma unroll
    for (int d = 1; d < 64; d <<= 1) {
      s1 += __shfl_xor(s1, d, 64);
      s2 += __shfl_xor(s2, d, 64);
    }
    const float mu   = s1 * (1.0f / 1024.0f);
    const float var  = fmaf(-mu, mu, s2 * (1.0f / 1024.0f));
    const float rstd = rsqrtf(var + 1e-5f);

    float ss = 0.f;
    #pragma unroll
    for (int c = 0; c < 4; ++c) {
      float*       pv = reinterpret_cast<float*>(&v[c]);
      const float* pw = reinterpret_cast<const float*>(&wv[c]);
      const float* pb = reinterpret_cast<const float*>(&bv4[c]);
      #pragma unroll
      for (int i = 0; i < 4; ++i) {
        float xh = (pv[i] - mu) * rstd;
        xh = fmaf(xh, pw[i], pb[i]);
        // 5*tanh(xh/5) = 5*(1 - 2/(e^{0.4*xh}+1))
        const float e = __expf(0.4f * xh);
        const float t = 1.f - 2.f * __builtin_amdgcn_rcpf(e + 1.f);
        const float xx = 5.f * t;
        ss = fmaf(xx, xx, ss);
        pv[i] = xx;
      }
    }
    #pragma unroll
    for (int d = 1; d < 64; d <<= 1) ss += __shfl_xor(ss, d, 64);

    // store bf16 A-fragments (swizzled)
    const int msw = m ^ (qA << 2) ^ sA;
    #pragma unroll
    for (int c = 0; c < 4; ++c) {
      const int gran = ((c * 8 + sA) * 4 + qA) * 16 + msw;
      uint2 pk;
      pk.x = f2bf(v[c].x) | ((unsigned int)f2bf(v[c].y) << 16);
      pk.y = f2bf(v[c].z) | ((unsigned int)f2bf(v[c].w) << 16);
      *(uint2*)&xs[gran * 8 + hfA * 4] = pk;
    }

    if (lane == 0) {
      const float nrm = sqrtf(ss);
      const float iv  = 1.f / fmaxf(nrm, 1e-5f);
      inv_s[m]  = iv;
      base_s[m] = fmaf(ss * iv, iv, 4.f);   // ||q||^2(=4) + ||xn||^2
    }
  }
  __syncthreads();

  // ---------------- Phase B: MFMA distances + argmax ------------------------
  {
    const int h = wave;
    const int q = lane >> 4, mm = lane & 15;

    short8 afr[8];
    #pragma unroll
    for (int s = 0; s < 8; ++s) {
      const int gran = (h * 8 + s) * 64 + q * 16 + (mm ^ (q << 2) ^ s);
      afr[s] = *(const short8*)&xs[gran * 8];
    }

    const short8* eb = (const short8*)ws_emb + (size_t)h * 2048 + lane;
    float4a acc[4];
    #pragma unroll
    for (int t = 0; t < 4; ++t) {
      #pragma unroll
      for (int r = 0; r < 4; ++r) acc[t][r] = 0.f;
    }
    #pragma unroll
    for (int t = 0; t < 4; ++t) {
      #pragma unroll
      for (int s = 0; s < 8; ++s) {
        const short8 bfr = eb[(t * 8 + s) * 64];
        acc[t] = __builtin_amdgcn_mfma_f32_16x16x32_bf16(afr[s], bfr, acc[t], 0, 0, 0);
      }
    }

    // acc[t][r] = dist[row=q*4+r][code=t*16+mm]
    #pragma unroll
    for (int r = 0; r < 4; ++r) {
      float bv = acc[0][r];
      int   bi = mm;
      #pragma unroll
      for (int t = 1; t < 4; ++t) {
        if (acc[t][r] > bv) { bv = acc[t][r]; bi = t * 16 + mm; }
      }
      #pragma unroll
      for (int d = 1; d <= 8; d <<= 1) {
        const float ov = __shfl_xor(bv, d, 64);
        const int   oi = __shfl_xor(bi, d, 64);
        if (ov > bv || (ov == bv && oi < bi)) { bv = ov; bi = oi; }
      }
      if (mm == 0) {
        const int row = q * 4 + r;
        bidx_s[row][h] = bi;
        bval_s[row][h] = bv;
        flags_s[h][bi] = 1;
      }
    }
  }
  __syncthreads();

  // ---------------- Phase C: gather-write q; loss; present ------------------
  #pragma unroll
  for (int rr = 0; rr < 4; ++rr) {
    const int row = wave * 4 + rr;
    const int4 bi = *(const int4*)(&bidx_s[row][0]);
    const float4 q0 = *(const float4*)(emb + (size_t)(0 * NK + bi.x) * HD + lane * 4);
    const float4 q1 = *(const float4*)(emb + (size_t)(1 * NK + bi.y) * HD + lane * 4);
    const float4 q2 = *(const float4*)(emb + (size_t)(2 * NK + bi.z) * HD + lane * 4);
    const float4 q3 = *(const float4*)(emb + (size_t)(3 * NK + bi.w) * HD + lane * 4);
    float* op = out + (size_t)(row0 + row) * DIM + lane * 4;
    *(float4*)(op + 0)   = q0;
    *(float4*)(op + 256) = q1;
    *(float4*)(op + 512) = q2;
    *(float4*)(op + 768) = q3;
  }

  if (wave == 0) {
    float lsum = 0.f;
    if (lane < RPB) {
      const float ds = (bval_s[lane][0] + bval_s[lane][1]) +
                       (bval_s[lane][2] + bval_s[lane][3]);
      lsum = fmaf(-2.f * inv_s[lane], ds, base_s[lane]);
    }
    #pragma unroll
    for (int d = 1; d <= 8; d <<= 1) lsum += __shfl_xor(lsum, d, 64);
    if (lane == 0) ws_loss[blockIdx.x] = lsum;
  } else if (wave == 1) {
    const int f = flags_s[0][lane] | flags_s[1][lane] |
                  flags_s[2][lane] | flags_s[3][lane];
    const unsigned long long mk = __ballot(f != 0);
    if (lane == 0) ws_mask[blockIdx.x] = mk;
  }
}

__global__ __launch_bounds__(256) void vq_fin(const float* __restrict__ ws,
                                              float* __restrict__ out) {
  __shared__ float ls[4];
  __shared__ unsigned long long ms[4];
  const float* ws_loss = ws;
  const unsigned long long* ws_mask = (const unsigned long long*)(ws + NBLK);

  const int tid = threadIdx.x, wave = tid >> 6, lane = tid & 63;
  float l = 0.f;
  unsigned long long m = 0ull;
  for (int i = tid; i < NBLK; i += 256) { l += ws_loss[i]; m |= ws_mask[i]; }
  #pragma unroll
  for (int s = 1; s < 64; s <<= 1) {
    l += __shfl_xor(l, s, 64);
    m |= __shfl_xor(m, s, 64);
  }
  if (lane == 0) { ls[wave] = l; ms[wave] = m; }
  __syncthreads();
  if (tid == 0) {
    const float total = (ls[0] + ls[1]) + (ls[2] + ls[3]);
    const unsigned long long mm = ms[0] | ms[1] | ms[2] | ms[3];
    out[33554432] = 0.25f * total / 33554432.0f;
    out[33554433] = (float)__popcll(mm);
  }
}

extern "C" void kernel_launch(void* const* d_in, const int* in_sizes, int n_in,
                              void* d_out, int out_size, void* d_ws, size_t ws_size,
                              hipStream_t stream) {
  const float* in  = (const float*)d_in[0];
  const float* lnw = (const float*)d_in[1];
  const float* lnb = (const float*)d_in[2];
  const float* emb = (const float*)d_in[3];
  float* out = (float*)d_out;
  float* ws  = (float*)d_ws;

  // ws layout: [0,2048) loss floats | [2048, 2048+4096) mask u64s |
  //            byte offset 24576: emb bf16 fragments (131072 B)
  unsigned short* ws_emb = (unsigned short*)((char*)d_ws + 24576);

  vq_pre<<<32, 256, 0, stream>>>(emb, ws_emb);
  vq_main<<<NBLK, THREADS, 0, stream>>>(in, lnw, lnb, emb, ws_emb, out, ws);
  vq_fin<<<1, 256, 0, stream>>>(ws, out);
}